// Round 1
// 712.326 us; speedup vs baseline: 1.1150x; 1.1150x over previous
//
#include <hip/hip_runtime.h>
#include <math.h>

#define B_ 2048
#define H_ 16
#define D_ 64
#define DE_ 32
#define NK_ 32
#define KP_ 32

// ws layout (fp32 offsets)
//   [0,1024)      pqFragH  (u16 x2048): [dstep][lane][8]
//   [1024,2048)   pqFragL  (u16 x2048)
#define OFF_WTL 2048   // WtL[d][i] d<64 i<128 (glw rows 0..127 transposed)
#define OFF_WTR 10240
#define OFF_SPT 18432  // SpT[d][i] = spw[i][d]
#define OFF_BL  22528  // b'_left[64], b'_right[64] (dv-part folded into bias)
#define WS_TOTAL 22656

typedef __attribute__((ext_vector_type(8)))  short short8;
typedef __attribute__((ext_vector_type(16))) float f32x16;
typedef __attribute__((ext_vector_type(4)))  unsigned int uint4v;

#define MFMA32(A,Bo,C) __builtin_amdgcn_mfma_f32_32x32x16_bf16(A,Bo,C,0,0,0)

__device__ __forceinline__ unsigned short bf16_rne(float x){
    unsigned u = __float_as_uint(x);
    unsigned r = u + 0x7fffu + ((u>>16)&1u);
    return (unsigned short)(r>>16);
}
__device__ __forceinline__ float bf16_to_f(unsigned short h){
    return __uint_as_float((unsigned)h << 16);
}
__device__ __forceinline__ unsigned pack2(unsigned short a, unsigned short b){
    return (unsigned)a | ((unsigned)b << 16);
}

// ---------------- precompute: pq frags, transposed weights, folded biases ---
__global__ void precompute(const float* __restrict__ pqb,
                           const float* __restrict__ qow,
                           const float* __restrict__ qob,
                           const float* __restrict__ glw,
                           const float* __restrict__ glb,
                           const float* __restrict__ grw,
                           const float* __restrict__ grb,
                           const float* __restrict__ spw,
                           const int*   __restrict__ depth_p,
                           float* __restrict__ ws)
{
    __shared__ float dvS[DE_];
    const int t = threadIdx.x;
    const int depth = depth_p[0];
    if (t < DE_) {
        int pi_ = t >> 1;
        float inv = expf(-(float)(2*pi_) * (logf(10000.f)/(float)DE_));
        float x = (float)depth * inv;
        dvS[t] = (t & 1) ? cosf(x) : sinf(x);
    }
    __syncthreads();
    int idx = blockIdx.x*256 + t;
    if (idx < 2048) {
        // pq = pqb + qob + dv@qow ; store bf16 hi/lo in MFMA-B-fragment order
        int q = idx >> 6, d = idx & 63;
        float acc = pqb[idx] + qob[idx];
        for (int i = 0; i < DE_; ++i) acc += dvS[i]*qow[i*2048 + idx];
        unsigned short hi = bf16_rne(acc);
        unsigned short lo = bf16_rne(acc - bf16_to_f(hi));
        int ds = d >> 4, h2 = (d>>3)&1, jj = d&7;
        int e = (ds*64 + (h2*32 + q))*8 + jj;
        unsigned short* wsu = (unsigned short*)ws;
        wsu[e]        = hi;
        wsu[2048 + e] = lo;
    } else if (idx < 2048 + 8192) {
        int j = idx - 2048; int d = j >> 7, i = j & 127;
        ws[OFF_WTL + j] = glw[i*64 + d];
    } else if (idx < 2048 + 16384) {
        int j = idx - (2048+8192); int d = j >> 7, i = j & 127;
        ws[OFF_WTR + j] = grw[i*64 + d];
    } else if (idx < 2048 + 16384 + 4096) {
        int j = idx - (2048+16384); int d = j >> 6, i = j & 63;
        ws[OFF_SPT + j] = spw[i*64 + d];
    } else if (idx < WS_TOTAL) {
        int j = idx - OFF_BL; int side = j >> 6, d = j & 63;
        const float* W = side ? grw : glw;
        float acc = side ? grb[d] : glb[d];
        for (int i = 0; i < DE_; ++i) acc += dvS[i]*W[(128+i)*64 + d];
        ws[OFF_BL + j] = acc;
    }
}

// ---------------- main: one block per (b,h); MFMA attention ----------------
__global__ __launch_bounds__(256, 4)
void gwm_main(const float* __restrict__ fL, const float* __restrict__ fR,
              const float* __restrict__ lng, const float* __restrict__ lnb,
              const float* __restrict__ sa,
              const float* __restrict__ wf, const float* __restrict__ wd,
              const float* __restrict__ wp, const int* __restrict__ depth_p,
              const float* __restrict__ ws, float* __restrict__ out)
{
    __shared__ __align__(16) unsigned short bankH16[NK_*64]; // swizzled rows
    __shared__ __align__(16) unsigned short bankL16[NK_*64];
    __shared__ __align__(16) unsigned short bTH16[64*40];    // [d][k] stride 40
    __shared__ __align__(16) unsigned short bTL16[64*40];
    __shared__ __align__(16) float partialS[8][64];
    __shared__ __align__(16) float lrS[128];                 // [lm(64), rm(64)]
    __shared__ __align__(16) float glS[64], grS[64], addS[64], gamS[64];

    const int t    = threadIdx.x;
    const int pair = blockIdx.x;
    const int h    = pair & (H_-1);
    const int wv   = t >> 6;
    const int lane = t & 63;
    const int depth = depth_p[0];

    // per-h phasor
    float wdv = wd[h];
    float sp = logf(1.f + expf(wdv));
    float decay = expf(-sp);
    float ang = wf[h] + wp[h] + (float)depth * 0.78539816339744831f;
    float pr  = decay * cosf(ang);
    float pim = decay * sinf(ang);

    const int kk = t >> 4;      // 0..15 bank row (fL) / +16 (rot)
    const int c  = t & 15;

    // --- Phase A: load + rotate; keep values in registers ---
    const size_t base = (size_t)pair * (16*64);
    float4 v4 = *(const float4*)(fL + base + kk*64 + 4*c);
    const float* fp = fR + base + kk*64;
    float2 fr2 = *(const float2*)(fp + 2*c);
    float2 fi2 = *(const float2*)(fp + 2*c + 32);
    float ro0 = pr*fr2.x - pim*fi2.x;
    float ro1 = pr*fr2.y - pim*fi2.y;
    float ro2 = pim*fr2.x + pr*fi2.x;
    float ro3 = pim*fr2.y + pr*fi2.y;

    // per-wave k-reduction (4 rows/wave) for the means
    float s0=v4.x, s1=v4.y, s2=v4.z, s3=v4.w;
    float u0=ro0, u1=ro1, u2=ro2, u3=ro3;
#define RED2(x) { x += __shfl_xor(x,16); x += __shfl_xor(x,32); }
    RED2(s0) RED2(s1) RED2(s2) RED2(s3)
    RED2(u0) RED2(u1) RED2(u2) RED2(u3)
    if (lane < 16) {
        *(float4*)(&partialS[wv][4*c])      = make_float4(s0,s1,s2,s3);
        *(float2*)(&partialS[4+wv][2*c])    = make_float2(u0,u1);
        *(float2*)(&partialS[4+wv][2*c+32]) = make_float2(u2,u3);
    }
    __syncthreads();

    // --- Phase B: means ---
    if (t < 128) {
        int d = t & 63, side = t >> 6;
        const float* p = &partialS[side*4][0];
        lrS[t] = (p[d] + p[64+d] + p[128+d] + p[192+d]) * 0.0625f;
    }
    __syncthreads();

    // --- Phase C: gates (waves 0,1), add-vector (wave 2), gamma (wave 3) ---
    if (wv < 2) {
        const float* Wt = ws + (wv ? OFF_WTR : OFF_WTL) + lane*128;
        float acc = ws[OFF_BL + wv*64 + lane];
        #pragma unroll 8
        for (int i = 0; i < 128; i += 4) {
            float4 w = *(const float4*)(Wt + i);
            float4 v = *(const float4*)(lrS + i);
            acc += w.x*v.x + w.y*v.y + w.z*v.z + w.w*v.w;
        }
        float g = 1.f / (1.f + __expf(-acc));
        (wv ? grS : glS)[lane] = g;
    } else if (wv == 2) {
        const float* Sp = ws + OFF_SPT + lane*64;
        float acc = 0.f;
        #pragma unroll 8
        for (int i = 0; i < 64; i += 4) {
            float4 w = *(const float4*)(Sp + i);
            float4 v = *(const float4*)(lrS + i);
            acc += w.x*v.x + w.y*v.y + w.z*v.z + w.w*v.w;
        }
        float ss = 1.f / (1.f + __expf(-sa[0]));
        addS[lane] = lnb[lane] + ss * acc;
    } else {
        gamS[lane] = lng[lane];
    }
    __syncthreads();

    // heavy wave rotates with blockIdx to spread MFMA across SIMDs
    const int hw = pair & 3;
    short8 qh0, qh1, qh2, qh3, ql0, ql1, ql2, ql3;
    if (wv == hw) {  // issue pq-fragment loads early (L2-resident)
        const unsigned short* wsu = (const unsigned short*)ws;
        qh0 = *(const short8*)(wsu + (0*64 + lane)*8);
        qh1 = *(const short8*)(wsu + (1*64 + lane)*8);
        qh2 = *(const short8*)(wsu + (2*64 + lane)*8);
        qh3 = *(const short8*)(wsu + (3*64 + lane)*8);
        ql0 = *(const short8*)(wsu + 2048 + (0*64 + lane)*8);
        ql1 = *(const short8*)(wsu + 2048 + (1*64 + lane)*8);
        ql2 = *(const short8*)(wsu + 2048 + (2*64 + lane)*8);
        ql3 = *(const short8*)(wsu + 2048 + (3*64 + lane)*8);
    }

    // --- Phase D: gate-scale in regs, write bf16 hi/lo bank (+transposed) ---
    {
        float4 g4 = *(const float4*)(glS + 4*c);
        float b0 = v4.x*g4.x, b1 = v4.y*g4.y, b2 = v4.z*g4.z, b3 = v4.w*g4.w;
        unsigned short H0=bf16_rne(b0), H1=bf16_rne(b1), H2=bf16_rne(b2), H3=bf16_rne(b3);
        unsigned short L0=bf16_rne(b0-bf16_to_f(H0)), L1=bf16_rne(b1-bf16_to_f(H1));
        unsigned short L2=bf16_rne(b2-bf16_to_f(H2)), L3=bf16_rne(b3-bf16_to_f(H3));
        const int m = (kk & 7) << 3;
        int eo = kk*64 + ((4*c) ^ m);
        *(uint2*)(bankH16 + eo) = make_uint2(pack2(H0,H1), pack2(H2,H3));
        *(uint2*)(bankL16 + eo) = make_uint2(pack2(L0,L1), pack2(L2,L3));
        bTH16[(4*c+0)*40 + kk] = H0; bTH16[(4*c+1)*40 + kk] = H1;
        bTH16[(4*c+2)*40 + kk] = H2; bTH16[(4*c+3)*40 + kk] = H3;
        bTL16[(4*c+0)*40 + kk] = L0; bTL16[(4*c+1)*40 + kk] = L1;
        bTL16[(4*c+2)*40 + kk] = L2; bTL16[(4*c+3)*40 + kk] = L3;

        float2 ga = *(const float2*)(grS + 2*c);
        float2 gb = *(const float2*)(grS + 2*c + 32);
        float w0 = ro0*ga.x, w1 = ro1*ga.y, w2 = ro2*gb.x, w3 = ro3*gb.y;
        unsigned short R0=bf16_rne(w0), R1=bf16_rne(w1), R2=bf16_rne(w2), R3=bf16_rne(w3);
        unsigned short S0_=bf16_rne(w0-bf16_to_f(R0)), S1_=bf16_rne(w1-bf16_to_f(R1));
        unsigned short S2_=bf16_rne(w2-bf16_to_f(R2)), S3_=bf16_rne(w3-bf16_to_f(R3));
        const int row = (16+kk)*64;
        *(unsigned*)(bankH16 + row + ((2*c)    ^ m)) = pack2(R0,R1);
        *(unsigned*)(bankH16 + row + ((2*c+32) ^ m)) = pack2(R2,R3);
        *(unsigned*)(bankL16 + row + ((2*c)    ^ m)) = pack2(S0_,S1_);
        *(unsigned*)(bankL16 + row + ((2*c+32) ^ m)) = pack2(S2_,S3_);
        bTH16[(2*c  )*40 + 16+kk] = R0; bTH16[(2*c+1 )*40 + 16+kk] = R1;
        bTH16[(2*c+32)*40 + 16+kk] = R2; bTH16[(2*c+33)*40 + 16+kk] = R3;
        bTL16[(2*c  )*40 + 16+kk] = S0_; bTL16[(2*c+1 )*40 + 16+kk] = S1_;
        bTL16[(2*c+32)*40 + 16+kk] = S2_; bTL16[(2*c+33)*40 + 16+kk] = S3_;
    }
    __syncthreads();

    // --- Phases E+F+epilogue: single (rotated) wave, MFMA split-bf16 ---
    if (wv == hw) {
        const int q  = lane & 31;   // E: bank row k ; F/out: query row
        const int hh = lane >> 5;

        // E: S^T(32k x 32q) = bank(32x64) @ pq^T ; 3-term split accumulation
        f32x16 A1, A2;
        #pragma unroll
        for (int i = 0; i < 16; ++i) { A1[i] = 0.f; A2[i] = 0.f; }
        const int sw = (q & 7) << 3;
        {
            int eo = q*64 + ((0*16 + hh*8) ^ sw);
            short8 ah = *(const short8*)(bankH16 + eo);
            short8 al = *(const short8*)(bankL16 + eo);
            A1 = MFMA32(ah, qh0, A1); A2 = MFMA32(ah, ql0, A2); A1 = MFMA32(al, qh0, A1);
        }
        {
            int eo = q*64 + ((1*16 + hh*8) ^ sw);
            short8 ah = *(const short8*)(bankH16 + eo);
            short8 al = *(const short8*)(bankL16 + eo);
            A1 = MFMA32(ah, qh1, A1); A2 = MFMA32(ah, ql1, A2); A1 = MFMA32(al, qh1, A1);
        }
        {
            int eo = q*64 + ((2*16 + hh*8) ^ sw);
            short8 ah = *(const short8*)(bankH16 + eo);
            short8 al = *(const short8*)(bankL16 + eo);
            A1 = MFMA32(ah, qh2, A1); A2 = MFMA32(ah, ql2, A2); A1 = MFMA32(al, qh2, A1);
        }
        {
            int eo = q*64 + ((3*16 + hh*8) ^ sw);
            short8 ah = *(const short8*)(bankH16 + eo);
            short8 al = *(const short8*)(bankL16 + eo);
            A1 = MFMA32(ah, qh3, A1); A2 = MFMA32(ah, ql3, A2); A1 = MFMA32(al, qh3, A1);
        }
        // softmax over k: lane holds 16 of 32 k's for query q; partner has rest
        float sc[16];
        #pragma unroll
        for (int i = 0; i < 16; ++i) sc[i] = (A1[i] + A2[i]) * 0.125f;
        float mx = sc[0];
        #pragma unroll
        for (int i = 1; i < 16; ++i) mx = fmaxf(mx, sc[i]);
        mx = fmaxf(mx, __shfl_xor(mx, 32));
        float ssum = 0.f;
        #pragma unroll
        for (int i = 0; i < 16; ++i) { sc[i] = __expf(sc[i] - mx); ssum += sc[i]; }
        ssum += __shfl_xor(ssum, 32);
        float inv = 1.f / ssum;
        // pack attn bf16 hi/lo; redistribute with partner lane (l^32)
        unsigned ch[8], cl[8], dh[8], dl[8];
        #pragma unroll
        for (int w = 0; w < 8; ++w) {
            float a0 = sc[2*w]*inv, a1 = sc[2*w+1]*inv;
            unsigned short Ha = bf16_rne(a0), Hb = bf16_rne(a1);
            unsigned short La = bf16_rne(a0 - bf16_to_f(Ha));
            unsigned short Lb = bf16_rne(a1 - bf16_to_f(Hb));
            ch[w] = pack2(Ha,Hb); cl[w] = pack2(La,Lb);
        }
        #pragma unroll
        for (int w = 0; w < 8; ++w) { dh[w] = __shfl_xor(ch[w],32); dl[w] = __shfl_xor(cl[w],32); }
        short8 Bh0, Bh1, Bl0, Bl1;
        if (hh == 0) {
            uint4v vh0 = {ch[0],ch[1],dh[0],dh[1]}, vl0 = {cl[0],cl[1],dl[0],dl[1]};
            uint4v vh1 = {ch[4],ch[5],dh[4],dh[5]}, vl1 = {cl[4],cl[5],dl[4],dl[5]};
            Bh0 = __builtin_bit_cast(short8, vh0); Bl0 = __builtin_bit_cast(short8, vl0);
            Bh1 = __builtin_bit_cast(short8, vh1); Bl1 = __builtin_bit_cast(short8, vl1);
        } else {
            uint4v vh0 = {dh[2],dh[3],ch[2],ch[3]}, vl0 = {dl[2],dl[3],cl[2],cl[3]};
            uint4v vh1 = {dh[6],dh[7],ch[6],ch[7]}, vl1 = {dl[6],dl[7],cl[6],cl[7]};
            Bh0 = __builtin_bit_cast(short8, vh0); Bl0 = __builtin_bit_cast(short8, vl0);
            Bh1 = __builtin_bit_cast(short8, vh1); Bl1 = __builtin_bit_cast(short8, vl1);
        }
        // F: P^T(64d x 32q) = bankT @ attn^T, two 32-row d-tiles
        f32x16 P0, P1;
        {
            f32x16 p1, p2;
            #pragma unroll
            for (int i = 0; i < 16; ++i) { p1[i] = 0.f; p2[i] = 0.f; }
            int e0 = q*40 + hh*8;
            short8 Ah = *(const short8*)(bTH16 + e0);
            short8 Al = *(const short8*)(bTL16 + e0);
            p1 = MFMA32(Ah, Bh0, p1); p2 = MFMA32(Ah, Bl0, p2); p1 = MFMA32(Al, Bh0, p1);
            int e1 = q*40 + 16 + hh*8;
            Ah = *(const short8*)(bTH16 + e1);
            Al = *(const short8*)(bTL16 + e1);
            p1 = MFMA32(Ah, Bh1, p1); p2 = MFMA32(Ah, Bl1, p2); p1 = MFMA32(Al, Bh1, p1);
            P0 = p1 + p2;
        }
        {
            f32x16 p1, p2;
            #pragma unroll
            for (int i = 0; i < 16; ++i) { p1[i] = 0.f; p2[i] = 0.f; }
            int e0 = (32+q)*40 + hh*8;
            short8 Ah = *(const short8*)(bTH16 + e0);
            short8 Al = *(const short8*)(bTL16 + e0);
            p1 = MFMA32(Ah, Bh0, p1); p2 = MFMA32(Ah, Bl0, p2); p1 = MFMA32(Al, Bh0, p1);
            int e1 = (32+q)*40 + 16 + hh*8;
            Ah = *(const short8*)(bTH16 + e1);
            Al = *(const short8*)(bTL16 + e1);
            p1 = MFMA32(Ah, Bh1, p1); p2 = MFMA32(Ah, Bl1, p2); p1 = MFMA32(Al, Bh1, p1);
            P1 = p1 + p2;
        }
        // layernorm over d (lane holds 32 of 64 d's for query q; partner rest)
        float sum = 0.f;
        #pragma unroll
        for (int i = 0; i < 16; ++i) sum += P0[i] + P1[i];
        sum += __shfl_xor(sum, 32);
        float mu = sum * (1.f/64.f);
        float ssd = 0.f;
        #pragma unroll
        for (int i = 0; i < 16; ++i) {
            float d1 = P0[i]-mu, d2 = P1[i]-mu;
            ssd += d1*d1 + d2*d2;
        }
        ssd += __shfl_xor(ssd, 32);
        float rinv = 1.f / sqrtf(ssd*(1.f/64.f) + 1e-5f);
        float* outp = out + (size_t)pair*(KP_*D_) + (size_t)q*64;
        #pragma unroll
        for (int grp = 0; grp < 4; ++grp) {
            int d0 = grp*8 + hh*4;
            float4 gm = *(const float4*)(gamS + d0);
            float4 ad = *(const float4*)(addS + d0);
            float4 o;
            o.x = (P0[grp*4+0]-mu)*rinv*gm.x + ad.x;
            o.y = (P0[grp*4+1]-mu)*rinv*gm.y + ad.y;
            o.z = (P0[grp*4+2]-mu)*rinv*gm.z + ad.z;
            o.w = (P0[grp*4+3]-mu)*rinv*gm.w + ad.w;
            *(float4*)(outp + d0) = o;
            int d1 = 32 + d0;
            float4 gm1 = *(const float4*)(gamS + d1);
            float4 ad1 = *(const float4*)(addS + d1);
            float4 o1;
            o1.x = (P1[grp*4+0]-mu)*rinv*gm1.x + ad1.x;
            o1.y = (P1[grp*4+1]-mu)*rinv*gm1.y + ad1.y;
            o1.z = (P1[grp*4+2]-mu)*rinv*gm1.z + ad1.z;
            o1.w = (P1[grp*4+3]-mu)*rinv*gm1.w + ad1.w;
            *(float4*)(outp + d1) = o1;
        }
    }
}

extern "C" void kernel_launch(void* const* d_in, const int* in_sizes, int n_in,
                              void* d_out, int out_size, void* d_ws, size_t ws_size,
                              hipStream_t stream) {
    const float* fL  = (const float*)d_in[0];
    const float* fR  = (const float*)d_in[1];
    const float* glw = (const float*)d_in[2];
    const float* glb = (const float*)d_in[3];
    const float* grw = (const float*)d_in[4];
    const float* grb = (const float*)d_in[5];
    const float* pqb = (const float*)d_in[6];
    const float* qow = (const float*)d_in[7];
    const float* qob = (const float*)d_in[8];
    const float* lng = (const float*)d_in[9];
    const float* lnb = (const float*)d_in[10];
    const float* spw = (const float*)d_in[11];
    const float* sa  = (const float*)d_in[12];
    const float* wf  = (const float*)d_in[13];
    const float* wd  = (const float*)d_in[14];
    const float* wp  = (const float*)d_in[15];
    const int* depth = (const int*)d_in[16];
    float* ws  = (float*)d_ws;
    float* out = (float*)d_out;

    hipLaunchKernelGGL(precompute, dim3((WS_TOTAL+255)/256), dim3(256), 0, stream,
                       pqb, qow, qob, glw, glb, grw, grb, spw, depth, ws);
    hipLaunchKernelGGL(gwm_main, dim3(B_*H_), dim3(256), 0, stream,
                       fL, fR, lng, lnb, sa, wf, wd, wp, depth, ws, out);
}

// Round 2
// 589.323 us; speedup vs baseline: 1.3477x; 1.2087x over previous
//
#include <hip/hip_runtime.h>
#include <math.h>

#define B_ 2048
#define H_ 16
#define D_ 64
#define DE_ 32
#define NK_ 32
#define KP_ 32

// ws layout (fp32 offsets)
//   [0,1024)      pqFragH  (u16 x2048): [dstep][lane][8]
//   [1024,2048)   pqFragL  (u16 x2048)
//   [2048,2176)   folded biases: b'_left[64], b'_right[64]
#define OFF_BL   2048
#define WS_TOTAL 2176

typedef __attribute__((ext_vector_type(8)))  short short8;
typedef __attribute__((ext_vector_type(16))) float f32x16;
typedef __attribute__((ext_vector_type(4)))  unsigned int uint4v;

#define MFMA32(A,Bo,C) __builtin_amdgcn_mfma_f32_32x32x16_bf16(A,Bo,C,0,0,0)

__device__ __forceinline__ unsigned short bf16_rne(float x){
    unsigned u = __float_as_uint(x);
    unsigned r = u + 0x7fffu + ((u>>16)&1u);
    return (unsigned short)(r>>16);
}
__device__ __forceinline__ float bf16_to_f(unsigned short h){
    return __uint_as_float((unsigned)h << 16);
}
__device__ __forceinline__ unsigned pack2(unsigned short a, unsigned short b){
    return (unsigned)a | ((unsigned)b << 16);
}

// ---------------- precompute: pq frags (bf16 hi/lo) + folded gate biases ----
__global__ void precompute(const float* __restrict__ pqb,
                           const float* __restrict__ qow,
                           const float* __restrict__ qob,
                           const float* __restrict__ glw,
                           const float* __restrict__ glb,
                           const float* __restrict__ grw,
                           const float* __restrict__ grb,
                           const int*   __restrict__ depth_p,
                           float* __restrict__ ws)
{
    __shared__ float dvS[DE_];
    const int t = threadIdx.x;
    const int depth = depth_p[0];
    if (t < DE_) {
        int pi_ = t >> 1;
        float inv = expf(-(float)(2*pi_) * (logf(10000.f)/(float)DE_));
        float x = (float)depth * inv;
        dvS[t] = (t & 1) ? cosf(x) : sinf(x);
    }
    __syncthreads();
    int idx = blockIdx.x*256 + t;
    if (idx < 2048) {
        // pq = pqb + qob + dv@qow ; store bf16 hi/lo in MFMA-B-fragment order
        int q = idx >> 6, d = idx & 63;
        float acc = pqb[idx] + qob[idx];
        for (int i = 0; i < DE_; ++i) acc += dvS[i]*qow[i*2048 + idx];
        unsigned short hi = bf16_rne(acc);
        unsigned short lo = bf16_rne(acc - bf16_to_f(hi));
        int ds = d >> 4, h2 = (d>>3)&1, jj = d&7;
        int e = (ds*64 + (h2*32 + q))*8 + jj;
        unsigned short* wsu = (unsigned short*)ws;
        wsu[e]        = hi;
        wsu[2048 + e] = lo;
    } else if (idx < WS_TOTAL) {
        int j = idx - OFF_BL; int side = j >> 6, d = j & 63;
        const float* W = side ? grw : glw;
        float acc = side ? grb[d] : glb[d];
        for (int i = 0; i < DE_; ++i) acc += dvS[i]*W[(128+i)*64 + d];
        ws[OFF_BL + j] = acc;
    }
}

// ---------------- main: one block per (b,h); MFMA attention ----------------
__global__ __launch_bounds__(256, 4)
void gwm_main(const float* __restrict__ fL, const float* __restrict__ fR,
              const float* __restrict__ glw, const float* __restrict__ grw,
              const float* __restrict__ spw,
              const float* __restrict__ lng, const float* __restrict__ lnb,
              const float* __restrict__ sa,
              const float* __restrict__ wf, const float* __restrict__ wd,
              const float* __restrict__ wp, const int* __restrict__ depth_p,
              const float* __restrict__ ws, float* __restrict__ out)
{
    __shared__ __align__(16) unsigned short bankH16[NK_*64]; // swizzled rows
    __shared__ __align__(16) unsigned short bankL16[NK_*64];
    __shared__ __align__(16) unsigned short bTH16[64*40];    // [d][k] stride 40
    __shared__ __align__(16) unsigned short bTL16[64*40];
    __shared__ __align__(16) float partialS[8][64];
    __shared__ __align__(16) float lrS[128];                 // [lm(64), rm(64)]
    __shared__ __align__(16) float glS[64], grS[64], addS[64], gamS[64];

    const int t    = threadIdx.x;
    const int pair = blockIdx.x;
    const int h    = pair & (H_-1);
    const int wv   = t >> 6;
    const int lane = t & 63;
    const int depth = depth_p[0];

    // per-h phasor
    float wdv = wd[h];
    float sp = logf(1.f + expf(wdv));
    float decay = expf(-sp);
    float ang = wf[h] + wp[h] + (float)depth * 0.78539816339744831f;
    float pr  = decay * cosf(ang);
    float pim = decay * sinf(ang);

    const int kk = t >> 4;      // 0..15 bank row (fL) / +16 (rot)
    const int c  = t & 15;

    // --- Phase A: load + rotate; keep values in registers ---
    const size_t base = (size_t)pair * (16*64);
    float4 v4 = *(const float4*)(fL + base + kk*64 + 4*c);
    const float* fp = fR + base + kk*64;
    float2 fr2 = *(const float2*)(fp + 2*c);
    float2 fi2 = *(const float2*)(fp + 2*c + 32);
    float ro0 = pr*fr2.x - pim*fi2.x;
    float ro1 = pr*fr2.y - pim*fi2.y;
    float ro2 = pim*fr2.x + pr*fi2.x;
    float ro3 = pim*fr2.y + pr*fi2.y;

    // per-wave k-reduction (4 rows/wave) for the means
    float s0=v4.x, s1=v4.y, s2=v4.z, s3=v4.w;
    float u0=ro0, u1=ro1, u2=ro2, u3=ro3;
#define RED2(x) { x += __shfl_xor(x,16); x += __shfl_xor(x,32); }
    RED2(s0) RED2(s1) RED2(s2) RED2(s3)
    RED2(u0) RED2(u1) RED2(u2) RED2(u3)
    if (lane < 16) {
        *(float4*)(&partialS[wv][4*c])      = make_float4(s0,s1,s2,s3);
        *(float2*)(&partialS[4+wv][2*c])    = make_float2(u0,u1);
        *(float2*)(&partialS[4+wv][2*c+32]) = make_float2(u2,u3);
    }
    __syncthreads();

    // --- Phase B: means ---
    if (t < 128) {
        int d = t & 63, side = t >> 6;
        const float* p = &partialS[side*4][0];
        lrS[t] = (p[d] + p[64+d] + p[128+d] + p[192+d]) * 0.0625f;
    }
    __syncthreads();

    // --- Phase C: gates (waves 0,1), skip/add (wave 2), gamma (wave 3) ---
    // Coalesced GEMV: lane l loads W[i0 + (l>>4)][4*(l&15) .. +4] -> the wave
    // covers 4 consecutive rows = 1024 contiguous bytes per instruction.
    {
        const int g  = lane >> 4;        // row-within-group 0..3
        const int c4 = (lane & 15) * 4;  // output d-quad
        if (wv < 2) {
            const float* W = wv ? grw : glw;
            float4 bb = *(const float4*)(ws + OFF_BL + wv*64 + c4);
            float a0=0.f, a1=0.f, a2=0.f, a3=0.f;
            #pragma unroll 8
            for (int i0 = 0; i0 < 128; i0 += 4) {
                float4 w = *(const float4*)(W + (size_t)(i0+g)*64 + c4);
                float x = lrS[i0+g];
                a0 += x*w.x; a1 += x*w.y; a2 += x*w.z; a3 += x*w.w;
            }
            a0 += __shfl_xor(a0,16); a1 += __shfl_xor(a1,16);
            a2 += __shfl_xor(a2,16); a3 += __shfl_xor(a3,16);
            a0 += __shfl_xor(a0,32); a1 += __shfl_xor(a1,32);
            a2 += __shfl_xor(a2,32); a3 += __shfl_xor(a3,32);
            if (lane < 16) {
                float4 gg;
                gg.x = 1.f/(1.f + __expf(-(a0 + bb.x)));
                gg.y = 1.f/(1.f + __expf(-(a1 + bb.y)));
                gg.z = 1.f/(1.f + __expf(-(a2 + bb.z)));
                gg.w = 1.f/(1.f + __expf(-(a3 + bb.w)));
                *(float4*)((wv ? grS : glS) + c4) = gg;
            }
        } else if (wv == 2) {
            float4 lb = *(const float4*)(lnb + c4);
            float sigsa = 1.f / (1.f + __expf(-sa[0]));
            float a0=0.f, a1=0.f, a2=0.f, a3=0.f;
            #pragma unroll 8
            for (int i0 = 0; i0 < 64; i0 += 4) {
                float4 w = *(const float4*)(spw + (size_t)(i0+g)*64 + c4);
                float x = lrS[i0+g];   // left mean
                a0 += x*w.x; a1 += x*w.y; a2 += x*w.z; a3 += x*w.w;
            }
            a0 += __shfl_xor(a0,16); a1 += __shfl_xor(a1,16);
            a2 += __shfl_xor(a2,16); a3 += __shfl_xor(a3,16);
            a0 += __shfl_xor(a0,32); a1 += __shfl_xor(a1,32);
            a2 += __shfl_xor(a2,32); a3 += __shfl_xor(a3,32);
            if (lane < 16) {
                float4 av;
                av.x = lb.x + sigsa*a0; av.y = lb.y + sigsa*a1;
                av.z = lb.z + sigsa*a2; av.w = lb.w + sigsa*a3;
                *(float4*)(addS + c4) = av;
            }
        } else {
            gamS[lane] = lng[lane];
        }
    }
    __syncthreads();

    // heavy wave rotates with blockIdx to spread MFMA across SIMDs
    const int hw = pair & 3;
    short8 qh0, qh1, qh2, qh3, ql0, ql1, ql2, ql3;
    if (wv == hw) {  // issue pq-fragment loads early (L2-resident)
        const unsigned short* wsu = (const unsigned short*)ws;
        qh0 = *(const short8*)(wsu + (0*64 + lane)*8);
        qh1 = *(const short8*)(wsu + (1*64 + lane)*8);
        qh2 = *(const short8*)(wsu + (2*64 + lane)*8);
        qh3 = *(const short8*)(wsu + (3*64 + lane)*8);
        ql0 = *(const short8*)(wsu + 2048 + (0*64 + lane)*8);
        ql1 = *(const short8*)(wsu + 2048 + (1*64 + lane)*8);
        ql2 = *(const short8*)(wsu + 2048 + (2*64 + lane)*8);
        ql3 = *(const short8*)(wsu + 2048 + (3*64 + lane)*8);
    }

    // --- Phase D: gate-scale in regs, write bf16 hi/lo bank (+transposed) ---
    {
        float4 g4 = *(const float4*)(glS + 4*c);
        float b0 = v4.x*g4.x, b1 = v4.y*g4.y, b2 = v4.z*g4.z, b3 = v4.w*g4.w;
        unsigned short H0=bf16_rne(b0), H1=bf16_rne(b1), H2=bf16_rne(b2), H3=bf16_rne(b3);
        unsigned short L0=bf16_rne(b0-bf16_to_f(H0)), L1=bf16_rne(b1-bf16_to_f(H1));
        unsigned short L2=bf16_rne(b2-bf16_to_f(H2)), L3=bf16_rne(b3-bf16_to_f(H3));
        const int m = (kk & 7) << 3;
        int eo = kk*64 + ((4*c) ^ m);
        *(uint2*)(bankH16 + eo) = make_uint2(pack2(H0,H1), pack2(H2,H3));
        *(uint2*)(bankL16 + eo) = make_uint2(pack2(L0,L1), pack2(L2,L3));
        bTH16[(4*c+0)*40 + kk] = H0; bTH16[(4*c+1)*40 + kk] = H1;
        bTH16[(4*c+2)*40 + kk] = H2; bTH16[(4*c+3)*40 + kk] = H3;
        bTL16[(4*c+0)*40 + kk] = L0; bTL16[(4*c+1)*40 + kk] = L1;
        bTL16[(4*c+2)*40 + kk] = L2; bTL16[(4*c+3)*40 + kk] = L3;

        float2 ga = *(const float2*)(grS + 2*c);
        float2 gb = *(const float2*)(grS + 2*c + 32);
        float w0 = ro0*ga.x, w1 = ro1*ga.y, w2 = ro2*gb.x, w3 = ro3*gb.y;
        unsigned short R0=bf16_rne(w0), R1=bf16_rne(w1), R2=bf16_rne(w2), R3=bf16_rne(w3);
        unsigned short S0_=bf16_rne(w0-bf16_to_f(R0)), S1_=bf16_rne(w1-bf16_to_f(R1));
        unsigned short S2_=bf16_rne(w2-bf16_to_f(R2)), S3_=bf16_rne(w3-bf16_to_f(R3));
        const int row = (16+kk)*64;
        *(unsigned*)(bankH16 + row + ((2*c)    ^ m)) = pack2(R0,R1);
        *(unsigned*)(bankH16 + row + ((2*c+32) ^ m)) = pack2(R2,R3);
        *(unsigned*)(bankL16 + row + ((2*c)    ^ m)) = pack2(S0_,S1_);
        *(unsigned*)(bankL16 + row + ((2*c+32) ^ m)) = pack2(S2_,S3_);
        bTH16[(2*c  )*40 + 16+kk] = R0; bTH16[(2*c+1 )*40 + 16+kk] = R1;
        bTH16[(2*c+32)*40 + 16+kk] = R2; bTH16[(2*c+33)*40 + 16+kk] = R3;
        bTL16[(2*c  )*40 + 16+kk] = S0_; bTL16[(2*c+1 )*40 + 16+kk] = S1_;
        bTL16[(2*c+32)*40 + 16+kk] = S2_; bTL16[(2*c+33)*40 + 16+kk] = S3_;
    }
    __syncthreads();

    // --- Phases E+F+epilogue: single (rotated) wave, MFMA split-bf16 ---
    if (wv == hw) {
        const int q  = lane & 31;   // E: bank row k ; F/out: query row
        const int hh = lane >> 5;

        // E: S^T(32k x 32q) = bank(32x64) @ pq^T ; 3 accumulator chains
        f32x16 A1, A2, A3;
        #pragma unroll
        for (int i = 0; i < 16; ++i) { A1[i] = 0.f; A2[i] = 0.f; A3[i] = 0.f; }
        const int sw = (q & 7) << 3;
        {
            int eo = q*64 + ((0*16 + hh*8) ^ sw);
            short8 ah = *(const short8*)(bankH16 + eo);
            short8 al = *(const short8*)(bankL16 + eo);
            A1 = MFMA32(ah, qh0, A1); A2 = MFMA32(ah, ql0, A2); A3 = MFMA32(al, qh0, A3);
        }
        {
            int eo = q*64 + ((1*16 + hh*8) ^ sw);
            short8 ah = *(const short8*)(bankH16 + eo);
            short8 al = *(const short8*)(bankL16 + eo);
            A1 = MFMA32(ah, qh1, A1); A2 = MFMA32(ah, ql1, A2); A3 = MFMA32(al, qh1, A3);
        }
        {
            int eo = q*64 + ((2*16 + hh*8) ^ sw);
            short8 ah = *(const short8*)(bankH16 + eo);
            short8 al = *(const short8*)(bankL16 + eo);
            A1 = MFMA32(ah, qh2, A1); A2 = MFMA32(ah, ql2, A2); A3 = MFMA32(al, qh2, A3);
        }
        {
            int eo = q*64 + ((3*16 + hh*8) ^ sw);
            short8 ah = *(const short8*)(bankH16 + eo);
            short8 al = *(const short8*)(bankL16 + eo);
            A1 = MFMA32(ah, qh3, A1); A2 = MFMA32(ah, ql3, A2); A3 = MFMA32(al, qh3, A3);
        }
        // softmax over k: lane holds 16 of 32 k's for query q; partner has rest
        float sc[16];
        #pragma unroll
        for (int i = 0; i < 16; ++i) sc[i] = (A1[i] + A2[i] + A3[i]) * 0.125f;
        float mx = sc[0];
        #pragma unroll
        for (int i = 1; i < 16; ++i) mx = fmaxf(mx, sc[i]);
        mx = fmaxf(mx, __shfl_xor(mx, 32));
        float ssum = 0.f;
        #pragma unroll
        for (int i = 0; i < 16; ++i) { sc[i] = __expf(sc[i] - mx); ssum += sc[i]; }
        ssum += __shfl_xor(ssum, 32);
        float inv = 1.f / ssum;
        // pack attn bf16 hi/lo; redistribute with partner lane (l^32)
        unsigned ch[8], cl[8], dh[8], dl[8];
        #pragma unroll
        for (int w = 0; w < 8; ++w) {
            float a0 = sc[2*w]*inv, a1 = sc[2*w+1]*inv;
            unsigned short Ha = bf16_rne(a0), Hb = bf16_rne(a1);
            unsigned short La = bf16_rne(a0 - bf16_to_f(Ha));
            unsigned short Lb = bf16_rne(a1 - bf16_to_f(Hb));
            ch[w] = pack2(Ha,Hb); cl[w] = pack2(La,Lb);
        }
        #pragma unroll
        for (int w = 0; w < 8; ++w) { dh[w] = __shfl_xor(ch[w],32); dl[w] = __shfl_xor(cl[w],32); }
        short8 Bh0, Bh1, Bl0, Bl1;
        if (hh == 0) {
            uint4v vh0 = {ch[0],ch[1],dh[0],dh[1]}, vl0 = {cl[0],cl[1],dl[0],dl[1]};
            uint4v vh1 = {ch[4],ch[5],dh[4],dh[5]}, vl1 = {cl[4],cl[5],dl[4],dl[5]};
            Bh0 = __builtin_bit_cast(short8, vh0); Bl0 = __builtin_bit_cast(short8, vl0);
            Bh1 = __builtin_bit_cast(short8, vh1); Bl1 = __builtin_bit_cast(short8, vl1);
        } else {
            uint4v vh0 = {dh[2],dh[3],ch[2],ch[3]}, vl0 = {dl[2],dl[3],cl[2],cl[3]};
            uint4v vh1 = {dh[6],dh[7],ch[6],ch[7]}, vl1 = {dl[6],dl[7],cl[6],cl[7]};
            Bh0 = __builtin_bit_cast(short8, vh0); Bl0 = __builtin_bit_cast(short8, vl0);
            Bh1 = __builtin_bit_cast(short8, vh1); Bl1 = __builtin_bit_cast(short8, vl1);
        }
        // F: P^T(64d x 32q) = bankT @ attn^T, two 32-row d-tiles
        f32x16 P0, P1;
        {
            f32x16 p1, p2;
            #pragma unroll
            for (int i = 0; i < 16; ++i) { p1[i] = 0.f; p2[i] = 0.f; }
            int e0 = q*40 + hh*8;
            short8 Ah = *(const short8*)(bTH16 + e0);
            short8 Al = *(const short8*)(bTL16 + e0);
            p1 = MFMA32(Ah, Bh0, p1); p2 = MFMA32(Ah, Bl0, p2); p1 = MFMA32(Al, Bh0, p1);
            int e1 = q*40 + 16 + hh*8;
            Ah = *(const short8*)(bTH16 + e1);
            Al = *(const short8*)(bTL16 + e1);
            p1 = MFMA32(Ah, Bh1, p1); p2 = MFMA32(Ah, Bl1, p2); p2 = MFMA32(Al, Bh1, p2);
            P0 = p1 + p2;
        }
        {
            f32x16 p1, p2;
            #pragma unroll
            for (int i = 0; i < 16; ++i) { p1[i] = 0.f; p2[i] = 0.f; }
            int e0 = (32+q)*40 + hh*8;
            short8 Ah = *(const short8*)(bTH16 + e0);
            short8 Al = *(const short8*)(bTL16 + e0);
            p1 = MFMA32(Ah, Bh0, p1); p2 = MFMA32(Ah, Bl0, p2); p1 = MFMA32(Al, Bh0, p1);
            int e1 = (32+q)*40 + 16 + hh*8;
            Ah = *(const short8*)(bTH16 + e1);
            Al = *(const short8*)(bTL16 + e1);
            p1 = MFMA32(Ah, Bh1, p1); p2 = MFMA32(Ah, Bl1, p2); p2 = MFMA32(Al, Bh1, p2);
            P1 = p1 + p2;
        }
        // layernorm over d (lane holds 32 of 64 d's for query q; partner rest)
        float sum = 0.f;
        #pragma unroll
        for (int i = 0; i < 16; ++i) sum += P0[i] + P1[i];
        sum += __shfl_xor(sum, 32);
        float mu = sum * (1.f/64.f);
        float ssd = 0.f;
        #pragma unroll
        for (int i = 0; i < 16; ++i) {
            float d1 = P0[i]-mu, d2 = P1[i]-mu;
            ssd += d1*d1 + d2*d2;
        }
        ssd += __shfl_xor(ssd, 32);
        float rinv = 1.f / sqrtf(ssd*(1.f/64.f) + 1e-5f);
        float* outp = out + (size_t)pair*(KP_*D_) + (size_t)q*64;
        #pragma unroll
        for (int grp = 0; grp < 4; ++grp) {
            int d0 = grp*8 + hh*4;
            float4 gm = *(const float4*)(gamS + d0);
            float4 ad = *(const float4*)(addS + d0);
            float4 o;
            o.x = (P0[grp*4+0]-mu)*rinv*gm.x + ad.x;
            o.y = (P0[grp*4+1]-mu)*rinv*gm.y + ad.y;
            o.z = (P0[grp*4+2]-mu)*rinv*gm.z + ad.z;
            o.w = (P0[grp*4+3]-mu)*rinv*gm.w + ad.w;
            *(float4*)(outp + d0) = o;
            int d1 = 32 + d0;
            float4 gm1 = *(const float4*)(gamS + d1);
            float4 ad1 = *(const float4*)(addS + d1);
            float4 o1;
            o1.x = (P1[grp*4+0]-mu)*rinv*gm1.x + ad1.x;
            o1.y = (P1[grp*4+1]-mu)*rinv*gm1.y + ad1.y;
            o1.z = (P1[grp*4+2]-mu)*rinv*gm1.z + ad1.z;
            o1.w = (P1[grp*4+3]-mu)*rinv*gm1.w + ad1.w;
            *(float4*)(outp + d1) = o1;
        }
    }
}

extern "C" void kernel_launch(void* const* d_in, const int* in_sizes, int n_in,
                              void* d_out, int out_size, void* d_ws, size_t ws_size,
                              hipStream_t stream) {
    const float* fL  = (const float*)d_in[0];
    const float* fR  = (const float*)d_in[1];
    const float* glw = (const float*)d_in[2];
    const float* glb = (const float*)d_in[3];
    const float* grw = (const float*)d_in[4];
    const float* grb = (const float*)d_in[5];
    const float* pqb = (const float*)d_in[6];
    const float* qow = (const float*)d_in[7];
    const float* qob = (const float*)d_in[8];
    const float* lng = (const float*)d_in[9];
    const float* lnb = (const float*)d_in[10];
    const float* spw = (const float*)d_in[11];
    const float* sa  = (const float*)d_in[12];
    const float* wf  = (const float*)d_in[13];
    const float* wd  = (const float*)d_in[14];
    const float* wp  = (const float*)d_in[15];
    const int* depth = (const int*)d_in[16];
    float* ws  = (float*)d_ws;
    float* out = (float*)d_out;

    hipLaunchKernelGGL(precompute, dim3((WS_TOTAL+255)/256), dim3(256), 0, stream,
                       pqb, qow, qob, glw, glb, grw, grb, depth, ws);
    hipLaunchKernelGGL(gwm_main, dim3(B_*H_), dim3(256), 0, stream,
                       fL, fR, glw, grw, spw, lng, lnb, sa, wf, wd, wp, depth, ws, out);
}